// Round 2
// baseline (949.154 us; speedup 1.0000x reference)
//
#include <hip/hip_runtime.h>
#include <math.h>

// Problem constants (MahaClassifier): x[B,D], weight[C,D], weight2[D,D]
#define BN 4096
#define CN 32768
#define DN 2048
constexpr float EPS = 1e-12f;

// Native clang vector for nontemporal builtins (HIP float4 is a struct).
typedef float f4 __attribute__((ext_vector_type(4)));

// ---------------------------------------------------------------- k0: zero
__global__ void k0_zero(float* __restrict__ p, int n) {
    int i = blockIdx.x * blockDim.x + threadIdx.x;
    if (i < n) p[i] = 0.0f;
}

// ------------------------------------------- k1: colnorm2[k] = sum_r w2[r,k]^2
// grid: (DN/1024, DN/16) = (2,128), block 256. Each thread owns 4 consecutive
// columns (float4) for a 16-row chunk, then one atomicAdd per column.
__global__ void k1_colnorm(const float* __restrict__ w2, float* __restrict__ colnorm2) {
    int col = blockIdx.x * 1024 + threadIdx.x * 4;
    int r0  = blockIdx.y * 16;
    float4 acc = make_float4(0.f, 0.f, 0.f, 0.f);
    #pragma unroll
    for (int r = 0; r < 16; ++r) {
        const float4 w = *reinterpret_cast<const float4*>(w2 + (size_t)(r0 + r) * DN + col);
        acc.x += w.x * w.x; acc.y += w.y * w.y;
        acc.z += w.z * w.z; acc.w += w.w * w.w;
    }
    atomicAdd(&colnorm2[col + 0], acc.x);
    atomicAdd(&colnorm2[col + 1], acc.y);
    atomicAdd(&colnorm2[col + 2], acc.z);
    atomicAdd(&colnorm2[col + 3], acc.w);
}

// --------------------------------- k2: s[j] = sum_k w2[j,k] / max(colnorm[k],eps)
// One wave (64 lanes) per row, 4 rows/block. inv[] staged in LDS; read as
// float4 (ds_read_b128, conflict-free).
__global__ void k2_rowsum(const float* __restrict__ w2, const float* __restrict__ colnorm2,
                          float* __restrict__ s) {
    __shared__ __align__(16) float inv[DN];
    for (int i = threadIdx.x; i < DN; i += 256)
        inv[i] = 1.0f / fmaxf(sqrtf(colnorm2[i]), EPS);
    __syncthreads();

    int wave = threadIdx.x >> 6;
    int lane = threadIdx.x & 63;
    int j = blockIdx.x * 4 + wave;
    const float* row = w2 + (size_t)j * DN;
    float acc = 0.0f;
    #pragma unroll
    for (int it = 0; it < DN / 256; ++it) {
        int k = it * 256 + lane * 4;
        float4 w = *reinterpret_cast<const float4*>(row + k);
        float4 iv = *reinterpret_cast<const float4*>(&inv[k]);
        acc += w.x * iv.x + w.y * iv.y + w.z * iv.z + w.w * iv.w;
    }
    #pragma unroll
    for (int off = 32; off > 0; off >>= 1) acc += __shfl_down(acc, off, 64);
    if (lane == 0) s[j] = acc;
}

// ---------------- k3: xs[i] = (x_i . s)/||x_i||  and  ms[c] = (w_c . s)/||w_c||
// One wave per TWO rows, processed interleaved (4 independent FMA chains,
// 16 outstanding loads) so the shfl-reduce latency of one row hides under
// the other. s held entirely in registers (8 float4/lane), no LDS.
__global__ void k3_dots(const float* __restrict__ x, const float* __restrict__ w,
                        const float* __restrict__ s,
                        float* __restrict__ xs, float* __restrict__ ms) {
    int wave = threadIdx.x >> 6;
    int lane = threadIdx.x & 63;
    int wid  = blockIdx.x * 4 + wave;   // global wave id
    int rA   = wid * 2;                 // even; never straddles the BN boundary
    int rB   = rA + 1;

    // lane-private fragment of s: element k = it*256 + lane*4 (+0..3)
    float4 sv[DN / 256];
    #pragma unroll
    for (int it = 0; it < DN / 256; ++it)
        sv[it] = *reinterpret_cast<const float4*>(s + it * 256 + lane * 4);

    const float* rowA = (rA < BN) ? x + (size_t)rA * DN : w + (size_t)(rA - BN) * DN;
    const float* rowB = (rB < BN) ? x + (size_t)rB * DN : w + (size_t)(rB - BN) * DN;

    float accA = 0.f, n2A = 0.f, accB = 0.f, n2B = 0.f;
    #pragma unroll
    for (int it = 0; it < DN / 256; ++it) {
        int k = it * 256 + lane * 4;
        float4 a = *reinterpret_cast<const float4*>(rowA + k);
        float4 b = *reinterpret_cast<const float4*>(rowB + k);
        accA += a.x * sv[it].x + a.y * sv[it].y + a.z * sv[it].z + a.w * sv[it].w;
        n2A  += a.x * a.x + a.y * a.y + a.z * a.z + a.w * a.w;
        accB += b.x * sv[it].x + b.y * sv[it].y + b.z * sv[it].z + b.w * sv[it].w;
        n2B  += b.x * b.x + b.y * b.y + b.z * b.z + b.w * b.w;
    }
    #pragma unroll
    for (int off = 32; off > 0; off >>= 1) {
        accA += __shfl_down(accA, off, 64);
        n2A  += __shfl_down(n2A, off, 64);
        accB += __shfl_down(accB, off, 64);
        n2B  += __shfl_down(n2B, off, 64);
    }
    if (lane == 0) {
        float vA = accA / fmaxf(sqrtf(n2A), EPS);
        float vB = accB / fmaxf(sqrtf(n2B), EPS);
        if (rA < BN) { xs[rA] = vA; xs[rB] = vB; }
        else         { ms[rA - BN] = vA; ms[rB - BN] = vB; }
    }
}

// --------------------------------------------- k4: out[i,c] = ms[c] - xs[i]
// Each thread owns 8 columns (2 float4, ms fragment in registers) and loops
// 64 rows: 1024 blocks total (4/CU), ms read once per 64 rows, nontemporal
// stores (out is write-once, never re-read).
#define K4_ROWS 64
__global__ void k4_write(const float* __restrict__ xs, const float* __restrict__ ms,
                         float* __restrict__ out) {
    int c  = blockIdx.x * 2048 + threadIdx.x * 8;
    int i0 = blockIdx.y * K4_ROWS;
    f4 m0 = *reinterpret_cast<const f4*>(ms + c);
    f4 m1 = *reinterpret_cast<const f4*>(ms + c + 4);
    #pragma unroll 8
    for (int r = 0; r < K4_ROWS; ++r) {
        float xv = xs[i0 + r];               // block-uniform -> scalar load
        float* o = out + (size_t)(i0 + r) * CN + c;
        __builtin_nontemporal_store(m0 - xv, reinterpret_cast<f4*>(o));
        __builtin_nontemporal_store(m1 - xv, reinterpret_cast<f4*>(o + 4));
    }
}

extern "C" void kernel_launch(void* const* d_in, const int* in_sizes, int n_in,
                              void* d_out, int out_size, void* d_ws, size_t ws_size,
                              hipStream_t stream) {
    const float* x  = (const float*)d_in[0];   // [B, D]
    const float* w  = (const float*)d_in[1];   // [C, D]
    const float* w2 = (const float*)d_in[2];   // [D, D]
    float* out = (float*)d_out;                // [B, C]

    // Workspace layout (floats): colnorm2[D] | s[D] | xs[B] | ms[C]
    float* colnorm2 = (float*)d_ws;
    float* s  = colnorm2 + DN;
    float* xs = s + DN;
    float* ms = xs + BN;

    k0_zero<<<(DN + 255) / 256, 256, 0, stream>>>(colnorm2, DN);
    k1_colnorm<<<dim3(DN / 1024, DN / 16), 256, 0, stream>>>(w2, colnorm2);
    k2_rowsum<<<DN / 4, 256, 0, stream>>>(w2, colnorm2, s);
    k3_dots<<<(BN + CN) / 8, 256, 0, stream>>>(x, w, s, xs, ms);
    k4_write<<<dim3(CN / 2048, BN / K4_ROWS), 256, 0, stream>>>(xs, ms, out);
}